// Round 1
// baseline (507.095 us; speedup 1.0000x reference)
//
#include <hip/hip_runtime.h>
#include <stdint.h>

// ---------------------------------------------------------------------------
// Phi3 attention block: QKV GEMM -> RoPE -> flash attn (causal, GQA) -> O GEMM
// B=2, S=2048, HID=2048, Hq=32, Hkv=8, D=64. fp32 in/out, bf16 MFMA inside.
// ---------------------------------------------------------------------------

typedef unsigned short u16;
typedef __bf16 bf16x8 __attribute__((ext_vector_type(8)));
typedef float f32x4 __attribute__((ext_vector_type(4)));
typedef unsigned short u16x8 __attribute__((ext_vector_type(8)));

__device__ __forceinline__ u16 f2bf(float f) {
  unsigned int u = __float_as_uint(f);
  u += 0x7fffu + ((u >> 16) & 1u);   // RNE
  return (u16)(u >> 16);
}

__device__ __forceinline__ void gload_lds16(const void* g, void* l) {
  __builtin_amdgcn_global_load_lds((const __attribute__((address_space(1))) void*)g,
                                   (__attribute__((address_space(3))) void*)l, 16, 0, 0);
}

// --------------------------- fp32 -> bf16 flat copy -------------------------
__global__ __launch_bounds__(256) void conv_bf16_kernel(const float* __restrict__ in,
                                                        u16* __restrict__ out, int n8) {
  int i = blockIdx.x * 256 + threadIdx.x;
  int stride = gridDim.x * 256;
  for (; i < n8; i += stride) {
    const float4* p = (const float4*)in + (size_t)i * 2;
    float4 a = p[0], b = p[1];
    u16x8 o;
    o[0] = f2bf(a.x); o[1] = f2bf(a.y); o[2] = f2bf(a.z); o[3] = f2bf(a.w);
    o[4] = f2bf(b.x); o[5] = f2bf(b.y); o[6] = f2bf(b.z); o[7] = f2bf(b.w);
    *(u16x8*)(out + (size_t)i * 8) = o;
  }
}

// --------------------- fp32 [R][C] -> bf16 transposed [C][R] ----------------
__global__ __launch_bounds__(256) void wtrans_kernel(const float* __restrict__ in,
                                                     u16* __restrict__ out, int R, int C) {
  __shared__ float tile[32][33];
  int tx = threadIdx.x & 31, ty = threadIdx.x >> 5;   // 32x8
  int col = blockIdx.x * 32 + tx;
  for (int j = ty; j < 32; j += 8)
    tile[j][tx] = in[(size_t)(blockIdx.y * 32 + j) * C + col];
  __syncthreads();
  int ocol = blockIdx.y * 32 + tx;                    // out col = in row
  for (int j = ty; j < 32; j += 8)
    out[(size_t)(blockIdx.x * 32 + j) * R + ocol] = f2bf(tile[tx][j]);
}

// ----------------------------- cos/sin tables -------------------------------
__global__ __launch_bounds__(256) void rope_table_kernel(float* __restrict__ cost,
                                                         float* __restrict__ sint) {
  int idx = blockIdx.x * 256 + threadIdx.x;           // 2048*32
  if (idx >= 2048 * 32) return;
  int p = idx >> 5, i = idx & 31;
  float invf = powf(10000.f, -(float)i / 32.f);
  float ang = (float)p * invf;
  cost[idx] = cosf(ang);
  sint[idx] = sinf(ang);
}

// --------------------------- bf16 GEMM, B transposed ------------------------
// C[M][N] fp32 = A[M][K] * Bt[N][K]^T.  128x128 tile, BK=32, 4 waves (2x2),
// 16x16x32 MFMA, global_load_lds width-16 staging (m97 structure).
__global__ __launch_bounds__(256) void gemm_bt_kernel(const u16* __restrict__ A,
                                                      const u16* __restrict__ Bt,
                                                      float* __restrict__ C,
                                                      int M, int N, int K) {
  __shared__ __align__(16) u16 lds_a[128 * 32];
  __shared__ __align__(16) u16 lds_b[128 * 32];
  const int tid = threadIdx.x;
  const int lane = tid & 63;
  const int w = tid >> 6;
  const int wr = w >> 1, wc = w & 1;
  const int brow = blockIdx.y * 128;
  const int bcol = blockIdx.x * 128;

  f32x4 acc[4][4] = {};

  // staging geometry: wave w stages rows [w*32, w*32+32) of each tile.
  // linear byte off in 8KB tile = w*2048 + i*1024 + lane*16; row = off/64 (64B rows)
  const int off0 = w * 2048 + lane * 16;

  for (int kt = 0; kt < K; kt += 32) {
#pragma unroll
    for (int i = 0; i < 2; ++i) {
      int off = off0 + i * 1024;
      int r = off >> 6;
      int ce = (off & 63) >> 1;
      gload_lds16(A + (size_t)(brow + r) * K + kt + ce,
                  lds_a + ((w * 2048 + i * 1024) >> 1));
      gload_lds16(Bt + (size_t)(bcol + r) * K + kt + ce,
                  lds_b + ((w * 2048 + i * 1024) >> 1));
    }
    __syncthreads();

    bf16x8 a[4], b[4];
#pragma unroll
    for (int m = 0; m < 4; ++m)
      a[m] = *(const bf16x8*)&lds_a[(wr * 64 + m * 16 + (lane & 15)) * 32 + (lane >> 4) * 8];
#pragma unroll
    for (int n = 0; n < 4; ++n)
      b[n] = *(const bf16x8*)&lds_b[(wc * 64 + n * 16 + (lane & 15)) * 32 + (lane >> 4) * 8];
#pragma unroll
    for (int m = 0; m < 4; ++m)
#pragma unroll
      for (int n = 0; n < 4; ++n)
        acc[m][n] = __builtin_amdgcn_mfma_f32_16x16x32_bf16(a[m], b[n], acc[m][n], 0, 0, 0);
    __syncthreads();
  }

#pragma unroll
  for (int m = 0; m < 4; ++m) {
    int row0 = brow + wr * 64 + m * 16 + (lane >> 4) * 4;
#pragma unroll
    for (int n = 0; n < 4; ++n) {
      int col = bcol + wc * 64 + n * 16 + (lane & 15);
#pragma unroll
      for (int j = 0; j < 4; ++j)
        C[(size_t)(row0 + j) * N + col] = acc[m][n][j];
    }
  }
}

// ------------------- RoPE + scatter q/k into head-major bf16 ----------------
// qkv fp32 [4096][3072] -> Q bf16 [B,32,S,64] (scaled 1/8), K bf16 [B,8,S,64]
__global__ __launch_bounds__(256) void rope_scatter_kernel(const float* __restrict__ qkv,
                                                           const int* __restrict__ pos_ids,
                                                           const float* __restrict__ cost,
                                                           const float* __restrict__ sint,
                                                           u16* __restrict__ Qo,
                                                           u16* __restrict__ Ko) {
  int t = blockIdx.x;                 // token 0..4095
  int b = t >> 11, s = t & 2047;
  int pos = pos_ids[t];
  const float* row = qkv + (size_t)t * 3072;
  int tid = threadIdx.x;

  // q: 32 heads x 32 rotation pairs
  for (int idx = tid; idx < 1024; idx += 256) {
    int hh = idx >> 5, i = idx & 31;
    float x1 = row[hh * 64 + i], x2 = row[hh * 64 + i + 32];
    float c = cost[pos * 32 + i], sn = sint[pos * 32 + i];
    float o1 = (x1 * c - x2 * sn) * 0.125f;   // fold 1/sqrt(64)
    float o2 = (x2 * c + x1 * sn) * 0.125f;
    size_t base = ((size_t)(b * 32 + hh) * 2048 + s) * 64;
    Qo[base + i] = f2bf(o1);
    Qo[base + i + 32] = f2bf(o2);
  }
  // k: 8 heads x 32 pairs
  {
    int hh = tid >> 5, i = tid & 31;
    float x1 = row[2048 + hh * 64 + i], x2 = row[2048 + hh * 64 + i + 32];
    float c = cost[pos * 32 + i], sn = sint[pos * 32 + i];
    float o1 = x1 * c - x2 * sn;
    float o2 = x2 * c + x1 * sn;
    size_t base = ((size_t)(b * 8 + hh) * 2048 + s) * 64;
    Ko[base + i] = f2bf(o1);
    Ko[base + i + 32] = f2bf(o2);
  }
}

// ---------------- V: qkv fp32 cols [2560,3072) -> Vt bf16 [B,8,64,S] --------
__global__ __launch_bounds__(256) void vtrans_kernel(const float* __restrict__ qkv,
                                                     u16* __restrict__ Vt) {
  __shared__ float tile[64][65];
  int b = blockIdx.x >> 3, hv = blockIdx.x & 7;
  int s0 = blockIdx.y * 64;
  int tid = threadIdx.x;
  for (int idx = tid; idx < 4096; idx += 256) {
    int tok = idx >> 6, c = idx & 63;
    tile[tok][c] = qkv[(size_t)(b * 2048 + s0 + tok) * 3072 + 2560 + hv * 64 + c];
  }
  __syncthreads();
  size_t obase = (size_t)(b * 8 + hv) * 64 * 2048;
  for (int idx = tid; idx < 4096; idx += 256) {
    int d = idx >> 6, si = idx & 63;
    Vt[obase + (size_t)d * 2048 + s0 + si] = f2bf(tile[si][d]);
  }
}

// ------------------------------- flash attention ----------------------------
// grid (S/64, B*32). Block: 4 waves; wave w owns q rows [qb+16w, qb+16w+16).
// K tile [64 k][64 d], Vt tile [64 d][64 k] in LDS, XOR-swizzled (T2) with
// pre-swizzled global source (gload_lds writes linearly).
__global__ __launch_bounds__(256) void attn_kernel(const u16* __restrict__ Q,
                                                   const u16* __restrict__ Kk,
                                                   const u16* __restrict__ Vt,
                                                   u16* __restrict__ O) {
  __shared__ __align__(16) u16 lds_k[64 * 64];
  __shared__ __align__(16) u16 lds_v[64 * 64];
  __shared__ __align__(16) u16 lds_p[4][16 * 80];   // per-wave P, padded stride 80

  const int tid = threadIdx.x;
  const int lane = tid & 63;
  const int w = tid >> 6;
  const int qt = blockIdx.x;
  const int bh = blockIdx.y;
  const int b = bh >> 5, h = bh & 31, hkv = (bh & 31) >> 2;
  const size_t qbase = (size_t)(b * 32 + h) * 2048 * 64;
  const size_t kbase = (size_t)(b * 8 + hkv) * 2048 * 64;
  const size_t vbase = (size_t)(b * 8 + hkv) * 64 * 2048;
  const int qb = qt * 64;

  // Q fragments in registers (already scaled by 1/8)
  bf16x8 aq[2];
  {
    int qrow = qb + w * 16 + (lane & 15);
    const u16* qp = Q + qbase + (size_t)qrow * 64 + (lane >> 4) * 8;
    aq[0] = *(const bf16x8*)(qp);
    aq[1] = *(const bf16x8*)(qp + 32);
  }

  f32x4 oacc[4] = {};
  float mrow[4], lrow[4];
#pragma unroll
  for (int j = 0; j < 4; ++j) { mrow[j] = -1e30f; lrow[j] = 0.f; }

  for (int kt = 0; kt <= qt; ++kt) {
    const int k0 = kt * 64;
    // stage K and Vt tiles; source pre-swizzled so swizzled reads see logical data
#pragma unroll
    for (int i = 0; i < 2; ++i) {
      int off = w * 2048 + i * 1024 + lane * 16;
      int sw = off ^ (((off >> 7) & 7) << 4);
      int r = sw >> 7;               // tile row (128B rows)
      int ce = (sw & 127) >> 1;      // element within row
      gload_lds16(Kk + kbase + (size_t)(k0 + r) * 64 + ce,
                  lds_k + ((w * 2048 + i * 1024) >> 1));
      gload_lds16(Vt + vbase + (size_t)r * 2048 + k0 + ce,
                  lds_v + ((w * 2048 + i * 1024) >> 1));
    }
    __syncthreads();

    // S = Q K^T (per wave: 16 q x 64 k)
    f32x4 sacc[4] = {};
#pragma unroll
    for (int n = 0; n < 4; ++n) {
      int row = n * 16 + (lane & 15);
#pragma unroll
      for (int c = 0; c < 2; ++c) {
        int byte = row * 128 + c * 64 + (lane >> 4) * 16;
        byte ^= ((row & 7) << 4);
        bf16x8 bk = *(const bf16x8*)&lds_k[byte >> 1];
        sacc[n] = __builtin_amdgcn_mfma_f32_16x16x32_bf16(aq[c], bk, sacc[n], 0, 0, 0);
      }
    }

    const bool diag = (kt == qt);
    float mnew[4], alpha[4], rsum[4];
#pragma unroll
    for (int j = 0; j < 4; ++j) {
      float mx = -1e30f;
#pragma unroll
      for (int n = 0; n < 4; ++n) {
        float s = sacc[n][j];
        if (diag) {
          int kcol = n * 16 + (lane & 15);
          int qrow = w * 16 + (lane >> 4) * 4 + j;
          if (kcol > qrow) { s = -1e30f; sacc[n][j] = s; }
        }
        mx = fmaxf(mx, s);
      }
      mx = fmaxf(mx, __shfl_xor(mx, 1));
      mx = fmaxf(mx, __shfl_xor(mx, 2));
      mx = fmaxf(mx, __shfl_xor(mx, 4));
      mx = fmaxf(mx, __shfl_xor(mx, 8));
      mnew[j] = fmaxf(mrow[j], mx);
      alpha[j] = __expf(mrow[j] - mnew[j]);
      mrow[j] = mnew[j];
      rsum[j] = 0.f;
    }
    // P = exp(S - m), stash to LDS in PV A-fragment layout
#pragma unroll
    for (int n = 0; n < 4; ++n)
#pragma unroll
      for (int j = 0; j < 4; ++j) {
        float p = __expf(sacc[n][j] - mnew[j]);
        rsum[j] += p;
        lds_p[w][((lane >> 4) * 4 + j) * 80 + n * 16 + (lane & 15)] = f2bf(p);
      }
#pragma unroll
    for (int j = 0; j < 4; ++j) {
      float rs = rsum[j];
      rs += __shfl_xor(rs, 1);
      rs += __shfl_xor(rs, 2);
      rs += __shfl_xor(rs, 4);
      rs += __shfl_xor(rs, 8);
      lrow[j] = lrow[j] * alpha[j] + rs;
    }
#pragma unroll
    for (int n = 0; n < 4; ++n)
#pragma unroll
      for (int j = 0; j < 4; ++j) oacc[n][j] *= alpha[j];

    asm volatile("s_waitcnt lgkmcnt(0)" ::: "memory");   // P writes -> P reads (intra-wave)

    // O += P V   (A = P [16 q x 64 k], B = V from Vt tile)
#pragma unroll
    for (int c = 0; c < 2; ++c) {
      bf16x8 pa = *(const bf16x8*)&lds_p[w][(lane & 15) * 80 + c * 32 + (lane >> 4) * 8];
#pragma unroll
      for (int n = 0; n < 4; ++n) {
        int row = n * 16 + (lane & 15);
        int byte = row * 128 + c * 64 + (lane >> 4) * 16;
        byte ^= ((row & 7) << 4);
        bf16x8 bv = *(const bf16x8*)&lds_v[byte >> 1];
        oacc[n] = __builtin_amdgcn_mfma_f32_16x16x32_bf16(pa, bv, oacc[n], 0, 0, 0);
      }
    }
    __syncthreads();
  }

  // epilogue: O/l -> bf16, layout [b*2048+s][h*64+d]
#pragma unroll
  for (int n = 0; n < 4; ++n) {
    int col = h * 64 + n * 16 + (lane & 15);
#pragma unroll
    for (int j = 0; j < 4; ++j) {
      int qrow = qb + w * 16 + (lane >> 4) * 4 + j;
      float v = oacc[n][j] / lrow[j];
      O[(size_t)(b * 2048 + qrow) * 2048 + col] = f2bf(v);
    }
  }
}

// ---------------------------------------------------------------------------
extern "C" void kernel_launch(void* const* d_in, const int* in_sizes, int n_in,
                              void* d_out, int out_size, void* d_ws, size_t ws_size,
                              hipStream_t stream) {
  const float* hidden = (const float*)d_in[0];
  const int* pos = (const int*)d_in[1];
  // d_in[2] = attention_mask: exact causal mask, implemented analytically
  const float* qkv_w = (const float*)d_in[3];
  const float* o_w = (const float*)d_in[4];
  float* out = (float*)d_out;
  char* ws = (char*)d_ws;

  u16* wqkvT  = (u16*)(ws + 0);                 // [3072][2048] bf16, 12.6MB
  u16* woT    = (u16*)(ws + 12582912);          // [2048][2048] bf16, 8.4MB
  u16* hidb   = (u16*)(ws + 20971520);          // [4096][2048] bf16, 16.8MB (reused as Q)
  float* qkvbuf = (float*)(ws + 37748736);      // [4096][3072] f32, 50.3MB (reused as attn out)
  u16* kb     = (u16*)(ws + 88080384);          // [2][8][2048][64] bf16
  u16* vtb    = (u16*)(ws + 92274688);          // [2][8][64][2048] bf16
  float* cost = (float*)(ws + 96468992);        // [2048][32]
  float* sint = (float*)(ws + 96731136);
  u16* qbuf   = hidb;                            // alias: hidden_bf16 dead after GEMM1
  u16* attnb  = (u16*)qkvbuf;                    // alias: qkv_buf dead after scatter

  conv_bf16_kernel<<<4096, 256, 0, stream>>>(hidden, hidb, 1048576);
  wtrans_kernel<<<dim3(96, 64), 256, 0, stream>>>(qkv_w, wqkvT, 2048, 3072);
  wtrans_kernel<<<dim3(64, 64), 256, 0, stream>>>(o_w, woT, 2048, 2048);
  rope_table_kernel<<<256, 256, 0, stream>>>(cost, sint);

  gemm_bt_kernel<<<dim3(24, 32), 256, 0, stream>>>(hidb, wqkvT, qkvbuf, 4096, 3072, 2048);

  rope_scatter_kernel<<<4096, 256, 0, stream>>>(qkvbuf, pos, cost, sint, qbuf, kb);
  vtrans_kernel<<<dim3(16, 32), 256, 0, stream>>>(qkvbuf, vtb);

  attn_kernel<<<dim3(32, 64), 256, 0, stream>>>(qbuf, kb, vtb, attnb);

  gemm_bt_kernel<<<dim3(16, 32), 256, 0, stream>>>(attnb, woT, out, 4096, 2048, 2048);
}

// Round 3
// 392.315 us; speedup vs baseline: 1.2926x; 1.2926x over previous
//
#include <hip/hip_runtime.h>
#include <stdint.h>

// ---------------------------------------------------------------------------
// Phi3 attention block: QKV GEMM -> RoPE -> flash attn (causal, GQA) -> O GEMM
// B=2, S=2048, HID=2048, Hq=32, Hkv=8, D=64. fp32 in/out, bf16 MFMA inside.
// Round 2 (resubmit): attn restructure — causal-paired blocks (uniform 33
// iters/block), swapped QK^T (S^T layout -> per-lane row softmax), in-register
// P exchange via cvt_pk + shfl (no P LDS, no lgkm drain, no bank conflicts).
// Fix vs last round: __exp2f -> exp2f (HIP has no __exp2f; compile error).
// ---------------------------------------------------------------------------

typedef unsigned short u16;
typedef __bf16 bf16x8 __attribute__((ext_vector_type(8)));
typedef float f32x4 __attribute__((ext_vector_type(4)));
typedef unsigned short u16x8 __attribute__((ext_vector_type(8)));
typedef unsigned int u32x4 __attribute__((ext_vector_type(4)));

__device__ __forceinline__ u16 f2bf(float f) {
  unsigned int u = __float_as_uint(f);
  u += 0x7fffu + ((u >> 16) & 1u);   // RNE
  return (u16)(u >> 16);
}

__device__ __forceinline__ unsigned cvt_pk_bf16(float lo, float hi) {
  unsigned r;
  asm("v_cvt_pk_bf16_f32 %0, %1, %2" : "=v"(r) : "v"(lo), "v"(hi));
  return r;
}

__device__ __forceinline__ void gload_lds16(const void* g, void* l) {
  __builtin_amdgcn_global_load_lds((const __attribute__((address_space(1))) void*)g,
                                   (__attribute__((address_space(3))) void*)l, 16, 0, 0);
}

// --------------------------- fp32 -> bf16 flat copy -------------------------
__global__ __launch_bounds__(256) void conv_bf16_kernel(const float* __restrict__ in,
                                                        u16* __restrict__ out, int n8) {
  int i = blockIdx.x * 256 + threadIdx.x;
  int stride = gridDim.x * 256;
  for (; i < n8; i += stride) {
    const float4* p = (const float4*)in + (size_t)i * 2;
    float4 a = p[0], b = p[1];
    u16x8 o;
    o[0] = f2bf(a.x); o[1] = f2bf(a.y); o[2] = f2bf(a.z); o[3] = f2bf(a.w);
    o[4] = f2bf(b.x); o[5] = f2bf(b.y); o[6] = f2bf(b.z); o[7] = f2bf(b.w);
    *(u16x8*)(out + (size_t)i * 8) = o;
  }
}

// --------------------- fp32 [R][C] -> bf16 transposed [C][R] ----------------
__global__ __launch_bounds__(256) void wtrans_kernel(const float* __restrict__ in,
                                                     u16* __restrict__ out, int R, int C) {
  __shared__ float tile[32][33];
  int tx = threadIdx.x & 31, ty = threadIdx.x >> 5;   // 32x8
  int col = blockIdx.x * 32 + tx;
  for (int j = ty; j < 32; j += 8)
    tile[j][tx] = in[(size_t)(blockIdx.y * 32 + j) * C + col];
  __syncthreads();
  int ocol = blockIdx.y * 32 + tx;                    // out col = in row
  for (int j = ty; j < 32; j += 8)
    out[(size_t)(blockIdx.x * 32 + j) * R + ocol] = f2bf(tile[tx][j]);
}

// ----------------------------- cos/sin tables -------------------------------
__global__ __launch_bounds__(256) void rope_table_kernel(float* __restrict__ cost,
                                                         float* __restrict__ sint) {
  int idx = blockIdx.x * 256 + threadIdx.x;           // 2048*32
  if (idx >= 2048 * 32) return;
  int p = idx >> 5, i = idx & 31;
  float invf = powf(10000.f, -(float)i / 32.f);
  float ang = (float)p * invf;
  cost[idx] = cosf(ang);
  sint[idx] = sinf(ang);
}

// --------------------------- bf16 GEMM, B transposed ------------------------
// C[M][N] fp32 = A[M][K] * Bt[N][K]^T.  128x128 tile, BK=32, 4 waves (2x2),
// 16x16x32 MFMA, global_load_lds width-16 staging (m97 structure).
__global__ __launch_bounds__(256) void gemm_bt_kernel(const u16* __restrict__ A,
                                                      const u16* __restrict__ Bt,
                                                      float* __restrict__ C,
                                                      int M, int N, int K) {
  __shared__ __align__(16) u16 lds_a[128 * 32];
  __shared__ __align__(16) u16 lds_b[128 * 32];
  const int tid = threadIdx.x;
  const int lane = tid & 63;
  const int w = tid >> 6;
  const int wr = w >> 1, wc = w & 1;
  const int brow = blockIdx.y * 128;
  const int bcol = blockIdx.x * 128;

  f32x4 acc[4][4] = {};

  const int off0 = w * 2048 + lane * 16;

  for (int kt = 0; kt < K; kt += 32) {
#pragma unroll
    for (int i = 0; i < 2; ++i) {
      int off = off0 + i * 1024;
      int r = off >> 6;
      int ce = (off & 63) >> 1;
      gload_lds16(A + (size_t)(brow + r) * K + kt + ce,
                  lds_a + ((w * 2048 + i * 1024) >> 1));
      gload_lds16(Bt + (size_t)(bcol + r) * K + kt + ce,
                  lds_b + ((w * 2048 + i * 1024) >> 1));
    }
    __syncthreads();

    bf16x8 a[4], b[4];
#pragma unroll
    for (int m = 0; m < 4; ++m)
      a[m] = *(const bf16x8*)&lds_a[(wr * 64 + m * 16 + (lane & 15)) * 32 + (lane >> 4) * 8];
#pragma unroll
    for (int n = 0; n < 4; ++n)
      b[n] = *(const bf16x8*)&lds_b[(wc * 64 + n * 16 + (lane & 15)) * 32 + (lane >> 4) * 8];
#pragma unroll
    for (int m = 0; m < 4; ++m)
#pragma unroll
      for (int n = 0; n < 4; ++n)
        acc[m][n] = __builtin_amdgcn_mfma_f32_16x16x32_bf16(a[m], b[n], acc[m][n], 0, 0, 0);
    __syncthreads();
  }

#pragma unroll
  for (int m = 0; m < 4; ++m) {
    int row0 = brow + wr * 64 + m * 16 + (lane >> 4) * 4;
#pragma unroll
    for (int n = 0; n < 4; ++n) {
      int col = bcol + wc * 64 + n * 16 + (lane & 15);
#pragma unroll
      for (int j = 0; j < 4; ++j)
        C[(size_t)(row0 + j) * N + col] = acc[m][n][j];
    }
  }
}

// ------------------- RoPE + scatter q/k into head-major bf16 ----------------
// qkv fp32 [4096][3072] -> Q bf16 [B,32,S,64] (scaled by log2e/8), K bf16 [B,8,S,64]
__global__ __launch_bounds__(256) void rope_scatter_kernel(const float* __restrict__ qkv,
                                                           const int* __restrict__ pos_ids,
                                                           const float* __restrict__ cost,
                                                           const float* __restrict__ sint,
                                                           u16* __restrict__ Qo,
                                                           u16* __restrict__ Ko) {
  int t = blockIdx.x;                 // token 0..4095
  int b = t >> 11, s = t & 2047;
  int pos = pos_ids[t];
  const float* row = qkv + (size_t)t * 3072;
  int tid = threadIdx.x;
  const float QSCALE = 0.125f * 1.44269504088896340736f;  // 1/sqrt(64) * log2(e)

  // q: 32 heads x 32 rotation pairs
  for (int idx = tid; idx < 1024; idx += 256) {
    int hh = idx >> 5, i = idx & 31;
    float x1 = row[hh * 64 + i], x2 = row[hh * 64 + i + 32];
    float c = cost[pos * 32 + i], sn = sint[pos * 32 + i];
    float o1 = (x1 * c - x2 * sn) * QSCALE;
    float o2 = (x2 * c + x1 * sn) * QSCALE;
    size_t base = ((size_t)(b * 32 + hh) * 2048 + s) * 64;
    Qo[base + i] = f2bf(o1);
    Qo[base + i + 32] = f2bf(o2);
  }
  // k: 8 heads x 32 pairs
  {
    int hh = tid >> 5, i = tid & 31;
    float x1 = row[2048 + hh * 64 + i], x2 = row[2048 + hh * 64 + i + 32];
    float c = cost[pos * 32 + i], sn = sint[pos * 32 + i];
    float o1 = x1 * c - x2 * sn;
    float o2 = x2 * c + x1 * sn;
    size_t base = ((size_t)(b * 8 + hh) * 2048 + s) * 64;
    Ko[base + i] = f2bf(o1);
    Ko[base + i + 32] = f2bf(o2);
  }
}

// ---------------- V: qkv fp32 cols [2560,3072) -> Vt bf16 [B,8,64,S] --------
__global__ __launch_bounds__(256) void vtrans_kernel(const float* __restrict__ qkv,
                                                     u16* __restrict__ Vt) {
  __shared__ float tile[64][65];
  int b = blockIdx.x >> 3, hv = blockIdx.x & 7;
  int s0 = blockIdx.y * 64;
  int tid = threadIdx.x;
  for (int idx = tid; idx < 4096; idx += 256) {
    int tok = idx >> 6, c = idx & 63;
    tile[tok][c] = qkv[(size_t)(b * 2048 + s0 + tok) * 3072 + 2560 + hv * 64 + c];
  }
  __syncthreads();
  size_t obase = (size_t)(b * 8 + hv) * 64 * 2048;
  for (int idx = tid; idx < 4096; idx += 256) {
    int d = idx >> 6, si = idx & 63;
    Vt[obase + (size_t)d * 2048 + s0 + si] = f2bf(tile[si][d]);
  }
}

// ------------------------------- flash attention ----------------------------
// grid (B*H=64, 16 pairs). Block = 4 waves; processes q-tiles {pair, 31-pair}
// sequentially -> every block does exactly 33 k-tile iterations (balanced).
// Wave w owns q rows [qt*64+16w, +16). Swapped QK^T: sacc = mfma(K, Q) gives
// S^T (lane&15 = q, lane>>4 and reg = k) so softmax row-reduce is 2 shfl and
// per-lane scalar m/l. P redistributed to PV A-fragments with cvt_pk+shfl.
__global__ __launch_bounds__(256) void attn_kernel(const u16* __restrict__ Q,
                                                   const u16* __restrict__ Kk,
                                                   const u16* __restrict__ Vt,
                                                   u16* __restrict__ O) {
  __shared__ __align__(16) u16 lds_k[64 * 64];
  __shared__ __align__(16) u16 lds_v[64 * 64];

  const int tid = threadIdx.x;
  const int lane = tid & 63;
  const int w = tid >> 6;
  const int g = lane >> 4;          // k-group within wave
  const int q = lane & 15;          // local q row (swapped layout)
  const int bh = blockIdx.x;
  const int b = bh >> 5, h = bh & 31, hkv = (bh & 31) >> 2;
  const size_t qbase = (size_t)(b * 32 + h) * 2048 * 64;
  const size_t kbase = (size_t)(b * 8 + hkv) * 2048 * 64;
  const size_t vbase = (size_t)(b * 8 + hkv) * 64 * 2048;
  const int pair = blockIdx.y;

  const int src0 = q | (((2 * g) & 3) << 4);        // P-exchange sources
  const int src1 = q | (((2 * g + 1) & 3) << 4);
  const bool hiN = g >= 2;
  const int srcQ = (lane & 48) | (4 * g);           // +j for alpha/l redistribute

  for (int half = 0; half < 2; ++half) {
    const int qt = half ? (31 - pair) : pair;
    const int qb = qt * 64;

    // Q fragments (B-operand layout; pre-scaled by log2e/8)
    bf16x8 aq[2];
    {
      const u16* qp = Q + qbase + (size_t)(qb + w * 16 + q) * 64 + g * 8;
      aq[0] = *(const bf16x8*)(qp);
      aq[1] = *(const bf16x8*)(qp + 32);
    }

    f32x4 oacc[4] = {};
    float m = -1e30f, l = 0.f;

    for (int kt = 0; kt <= qt; ++kt) {
      const int k0 = kt * 64;
      // stage K [64k][64d] and Vt [64d][64k] tiles, XOR-swizzled via source
#pragma unroll
      for (int i = 0; i < 2; ++i) {
        int off = w * 2048 + i * 1024 + lane * 16;
        int sw = off ^ (((off >> 7) & 7) << 4);
        int r = sw >> 7;
        int ce = (sw & 127) >> 1;
        gload_lds16(Kk + kbase + (size_t)(k0 + r) * 64 + ce,
                    lds_k + ((w * 2048 + i * 1024) >> 1));
        gload_lds16(Vt + vbase + (size_t)r * 2048 + k0 + ce,
                    lds_v + ((w * 2048 + i * 1024) >> 1));
      }
      __syncthreads();

      const bool diag = (kt == qt);
      const int nmax = diag ? w : 3;        // subtiles n>w fully masked on diag

      // S^T = K Q^T per wave: sacc[n][j] = S[k = k0+16n+4g+j][q row lane&15]
      f32x4 sacc[4] = {};
#pragma unroll
      for (int n = 0; n < 4; ++n) {
        if (n > nmax) break;
        int row = n * 16 + q;
#pragma unroll
        for (int c = 0; c < 2; ++c) {
          int byte = row * 128 + c * 64 + g * 16;
          byte ^= ((row & 7) << 4);
          bf16x8 ak = *(const bf16x8*)&lds_k[byte >> 1];
          sacc[n] = __builtin_amdgcn_mfma_f32_16x16x32_bf16(ak, aq[c], sacc[n], 0, 0, 0);
        }
      }

      if (diag) {
#pragma unroll
        for (int n = 0; n < 4; ++n)
#pragma unroll
          for (int j = 0; j < 4; ++j)
            if (n * 16 + 4 * g + j > w * 16 + q) sacc[n][j] = -1e30f;
      }

      // row max (per-lane 16 values, then across the 4 k-groups)
      float mx = sacc[0][0];
#pragma unroll
      for (int n = 0; n < 4; ++n)
#pragma unroll
        for (int j = 0; j < 4; ++j) mx = fmaxf(mx, sacc[n][j]);
      mx = fmaxf(mx, __shfl_xor(mx, 16, 64));
      mx = fmaxf(mx, __shfl_xor(mx, 32, 64));
      float mnew = fmaxf(m, mx);
      float alpha = exp2f(m - mnew);
      m = mnew;

      float p[4][4];
      float rs = 0.f;
#pragma unroll
      for (int n = 0; n < 4; ++n)
#pragma unroll
        for (int j = 0; j < 4; ++j) {
          float pv = exp2f(sacc[n][j] - mnew);
          p[n][j] = pv;
          rs += pv;
        }
      rs += __shfl_xor(rs, 16, 64);
      rs += __shfl_xor(rs, 32, 64);
      l = l * alpha + rs;

      // rescale O (alpha redistributed from q=lane&15 to q=4g+j layout)
#pragma unroll
      for (int j = 0; j < 4; ++j) {
        float aj = __shfl(alpha, srcQ + j, 64);
#pragma unroll
        for (int n = 0; n < 4; ++n) oacc[n][j] *= aj;
      }

      // pack P pairs: pk[n][s] = bf16x2 of (p[n][2s], p[n][2s+1])
      unsigned pk[4][2];
#pragma unroll
      for (int n = 0; n < 4; ++n) {
        pk[n][0] = cvt_pk_bf16(p[n][0], p[n][1]);
        pk[n][1] = cvt_pk_bf16(p[n][2], p[n][3]);
      }

      // O += P V: build A-frag a[c] (lane: P[q=lane&15][k=32c+8g+e]) via shfl
#pragma unroll
      for (int c = 0; c < 2; ++c) {
        if (diag && w < 2 && c == 1) break;   // k-chunk fully masked
        u32x4 wv;
        {
          int t0 = __shfl((int)pk[2 * c][0], src0, 64);
          int t1 = __shfl((int)pk[2 * c + 1][0], src0, 64);
          wv[0] = (unsigned)(hiN ? t1 : t0);
          t0 = __shfl((int)pk[2 * c][1], src0, 64);
          t1 = __shfl((int)pk[2 * c + 1][1], src0, 64);
          wv[1] = (unsigned)(hiN ? t1 : t0);
          t0 = __shfl((int)pk[2 * c][0], src1, 64);
          t1 = __shfl((int)pk[2 * c + 1][0], src1, 64);
          wv[2] = (unsigned)(hiN ? t1 : t0);
          t0 = __shfl((int)pk[2 * c][1], src1, 64);
          t1 = __shfl((int)pk[2 * c + 1][1], src1, 64);
          wv[3] = (unsigned)(hiN ? t1 : t0);
        }
        bf16x8 pa = __builtin_bit_cast(bf16x8, wv);
#pragma unroll
        for (int n = 0; n < 4; ++n) {
          int row = n * 16 + q;
          int byte = row * 128 + c * 64 + g * 16;
          byte ^= ((row & 7) << 4);
          bf16x8 bv = *(const bf16x8*)&lds_v[byte >> 1];
          oacc[n] = __builtin_amdgcn_mfma_f32_16x16x32_bf16(pa, bv, oacc[n], 0, 0, 0);
        }
      }
      __syncthreads();
    }

    // epilogue: O/l -> bf16, layout [b*2048+s][h*64+d]
    float linv[4];
#pragma unroll
    for (int j = 0; j < 4; ++j)
      linv[j] = __builtin_amdgcn_rcpf(__shfl(l, srcQ + j, 64));
#pragma unroll
    for (int n = 0; n < 4; ++n) {
      int col = h * 64 + n * 16 + q;
#pragma unroll
      for (int j = 0; j < 4; ++j) {
        int qrow = qb + w * 16 + 4 * g + j;
        O[(size_t)(b * 2048 + qrow) * 2048 + col] = f2bf(oacc[n][j] * linv[j]);
      }
    }
  }
}

// ---------------------------------------------------------------------------
extern "C" void kernel_launch(void* const* d_in, const int* in_sizes, int n_in,
                              void* d_out, int out_size, void* d_ws, size_t ws_size,
                              hipStream_t stream) {
  const float* hidden = (const float*)d_in[0];
  const int* pos = (const int*)d_in[1];
  // d_in[2] = attention_mask: exact causal mask, implemented analytically
  const float* qkv_w = (const float*)d_in[3];
  const float* o_w = (const float*)d_in[4];
  float* out = (float*)d_out;
  char* ws = (char*)d_ws;

  u16* wqkvT  = (u16*)(ws + 0);                 // [3072][2048] bf16, 12.6MB
  u16* woT    = (u16*)(ws + 12582912);          // [2048][2048] bf16, 8.4MB
  u16* hidb   = (u16*)(ws + 20971520);          // [4096][2048] bf16, 16.8MB (reused as Q)
  float* qkvbuf = (float*)(ws + 37748736);      // [4096][3072] f32, 50.3MB (reused as attn out)
  u16* kb     = (u16*)(ws + 88080384);          // [2][8][2048][64] bf16
  u16* vtb    = (u16*)(ws + 92274688);          // [2][8][64][2048] bf16
  float* cost = (float*)(ws + 96468992);        // [2048][32]
  float* sint = (float*)(ws + 96731136);
  u16* qbuf   = hidb;                            // alias: hidden_bf16 dead after GEMM1
  u16* attnb  = (u16*)qkvbuf;                    // alias: qkv_buf dead after scatter

  conv_bf16_kernel<<<4096, 256, 0, stream>>>(hidden, hidb, 1048576);
  wtrans_kernel<<<dim3(96, 64), 256, 0, stream>>>(qkv_w, wqkvT, 2048, 3072);
  wtrans_kernel<<<dim3(64, 64), 256, 0, stream>>>(o_w, woT, 2048, 2048);
  rope_table_kernel<<<256, 256, 0, stream>>>(cost, sint);

  gemm_bt_kernel<<<dim3(24, 32), 256, 0, stream>>>(hidb, wqkvT, qkvbuf, 4096, 3072, 2048);

  rope_scatter_kernel<<<4096, 256, 0, stream>>>(qkvbuf, pos, cost, sint, qbuf, kb);
  vtrans_kernel<<<dim3(16, 32), 256, 0, stream>>>(qkvbuf, vtb);

  attn_kernel<<<dim3(64, 16), 256, 0, stream>>>(qbuf, kb, vtb, attnb);

  gemm_bt_kernel<<<dim3(16, 32), 256, 0, stream>>>(attnb, woT, out, 4096, 2048, 2048);
}